// Round 5
// baseline (39346.933 us; speedup 1.0000x reference)
//
#include <hip/hip_runtime.h>

// FeatureAdaptation (deformable conv): B=2, CHI=CHO=256, H=W=128, K=9.
// R5: optimized VALU path (MFMA retry deferred to an inline-asm variant).
//  - coalesced channel-contiguous gather (R1-style), verified math from R2
//  - weights: 4x int4 vector loads per K-slice, prefetched one slice ahead
//  - T14 async-stage split: issue slice t+1 gathers before dot(t), LDS-write after
//  - double-buffered As2, fully unrolled 32x32 FMA dot (broadcast ds_read_b128)

typedef float f32x4v __attribute__((ext_vector_type(4)));

#define HH 128
#define WW 128
#define CIN 256
#define COUT 256
#define KK9 9
#define HW (HH * WW)            // 16384
#define KDIM (KK9 * CIN)        // 2304
#define NT (KDIM / 32)          // 72 slices of 32
#define BM 32
#define XT_PER_B (HW * CIN)     // 4194304 elems per batch

__device__ __forceinline__ ushort f2bf(float f) {
  union { float f; unsigned u; } v; v.f = f;
  unsigned u = v.u;
  u += 0x7FFFu + ((u >> 16) & 1u);   // RNE
  return (ushort)(u >> 16);
}
__device__ __forceinline__ float bf2f(ushort h) {
  union { unsigned u; float f; } v; v.u = ((unsigned)h) << 16; return v.f;
}

// ---------------- x (B,C,H,W) f32  ->  xT (B,H,W,C) bf16 ----------------
__global__ __launch_bounds__(256) void k_transpose(const float* __restrict__ x,
                                                   ushort* __restrict__ xT) {
  __shared__ ushort tile[64][130];
  const int bid = blockIdx.x;       // ((b*4 + cb)*128 + y)
  const int y  = bid & 127;
  const int t  = bid >> 7;
  const int cb = t & 3;
  const int b  = t >> 2;

  const int xl = threadIdx.x & 127;
  const int ch = threadIdx.x >> 7;
  const float* src = x + (size_t)(b * CIN + cb * 64) * HW + y * WW + xl;
#pragma unroll
  for (int i = 0; i < 32; ++i) {
    int c = ch * 32 + i;
    tile[c][xl] = f2bf(src[(size_t)c * HW]);
  }
  __syncthreads();
  const int c  = threadIdx.x & 63;
  const int xh = threadIdx.x >> 6;
  ushort* dst = xT + (size_t)b * XT_PER_B + (size_t)(y * WW) * CIN + cb * 64 + c;
#pragma unroll
  for (int i = 0; i < 32; ++i) {
    int xx = xh * 32 + i;
    dst[(size_t)xx * CIN] = tile[c][xx];
  }
}

// ---------------- conv_w (O,C,3,3) f32 -> Bm[o][k*256+c] bf16 ----------------
__global__ __launch_bounds__(256) void k_packw(const float* __restrict__ cw,
                                               ushort* __restrict__ Bm) {
  int idx = blockIdx.x * 256 + threadIdx.x;   // < 589824
  int o = idx / KDIM;
  int t = idx - o * KDIM;
  int k = t >> 8;
  int c = t & 255;
  Bm[idx] = f2bf(cw[(o * CIN + c) * KK9 + k]);
}

// ---------------- gather + VALU GEMM ----------------
// grid 1024 = B*H*(W/32); block 256 (4 waves). Block: 32 pixels x 256 out-ch.
// Thread tid owns out-channel o = tid for all 32 pixels.
__global__ __launch_bounds__(256, 2) void k_main2(
    const ushort* __restrict__ xT, const ushort* __restrict__ Bm,
    const float* __restrict__ scale, const float* __restrict__ ctr,
    const float* __restrict__ offw, const float* __restrict__ offb,
    const float* __restrict__ mskw, const float* __restrict__ mskb,
    const float* __restrict__ convb, float* __restrict__ out) {
  __shared__ float  As2[2][32][33];     // [buf][c_local][pixel], +1 pad
  __shared__ int4   moff[BM * KK9];     // 4 corner element-offsets
  __shared__ float4 mwt[BM * KK9];      // 4 corner weights (mask+validity folded)

  const int tid  = threadIdx.x;
  const int lane = tid & 63;
  const int wid  = tid >> 6;
  const int mb   = blockIdx.x;
  const int b    = mb >> 9;
  const int rem  = mb & 511;
  const int h    = rem >> 2;
  const int w0   = (rem & 3) << 5;

  // ---- prologue: per (pixel,k) bilinear metadata (R2-verified)
  for (int idx = tid; idx < BM * KK9; idx += 256) {
    int p = idx / 9;
    int k = idx - p * 9;
    int w = w0 + p;
    float sc = scale[b * HW + h * WW + w];
    float ct = ctr[b * HW + h * WW + w];
    float dy = sc * offw[2 * k]     + offb[2 * k];
    float dx = sc * offw[2 * k + 1] + offb[2 * k + 1];
    float mk = 1.0f / (1.0f + __expf(-(ct * mskw[k] + mskb[k])));
    float ys = (float)(h + (k / 3) - 1) + dy;
    float xs = (float)(w + (k % 3) - 1) + dx;
    float y0 = floorf(ys), x0 = floorf(xs);
    float wy1 = ys - y0, wx1 = xs - x0;
    float wy0 = 1.f - wy1, wx0 = 1.f - wx1;
    int offc[4]; float wtc[4];
#pragma unroll
    for (int a = 0; a < 2; ++a)
#pragma unroll
      for (int bb = 0; bb < 2; ++bb) {
        float yc = y0 + (float)a, xc = x0 + (float)bb;
        bool valid = (yc >= 0.f) && (yc <= 127.f) && (xc >= 0.f) && (xc <= 127.f);
        int yi = (int)fminf(fmaxf(yc, 0.f), 127.f);
        int xi = (int)fminf(fmaxf(xc, 0.f), 127.f);
        offc[a * 2 + bb] = (yi * WW + xi) * CIN;
        wtc[a * 2 + bb]  = (a ? wy1 : wy0) * (bb ? wx1 : wx0) * mk * (valid ? 1.f : 0.f);
      }
    moff[idx] = make_int4(offc[0], offc[1], offc[2], offc[3]);
    mwt[idx]  = make_float4(wtc[0], wtc[1], wtc[2], wtc[3]);
  }
  __syncthreads();

  const ushort* xTb = xT + (size_t)b * XT_PER_B;
  const int cl   = lane & 31;          // channel lane (coalesced gather)
  const int half = lane >> 5;

  float acc[32];
#pragma unroll
  for (int p = 0; p < 32; ++p) acc[p] = 0.f;

  // per-thread weight row (o = tid), 64 B per slice as 4x int4
  const ushort* wrow = Bm + (size_t)tid * KDIM;

  ushort g[4][4];     // staged gather: [pass][corner]

  // issue slice-t corner loads into regs (coalesced: 32 lanes x 2B contiguous)
  auto ISSUE = [&](int t) {
    const int k  = t >> 3;
    const int c0 = (t & 7) << 5;
#pragma unroll
    for (int pass = 0; pass < 4; ++pass) {
      int p   = wid * 8 + pass * 2 + half;
      int4 off = moff[p * 9 + k];
      int c = c0 + cl;
      g[pass][0] = xTb[off.x + c];
      g[pass][1] = xTb[off.y + c];
      g[pass][2] = xTb[off.z + c];
      g[pass][3] = xTb[off.w + c];
    }
  };
  // combine corners with weights, write slice into As2[buf]
  auto WRITE = [&](int t, int buf) {
    const int k = t >> 3;
#pragma unroll
    for (int pass = 0; pass < 4; ++pass) {
      int p = wid * 8 + pass * 2 + half;
      float4 wt = mwt[p * 9 + k];
      float v = wt.x * bf2f(g[pass][0]) + wt.y * bf2f(g[pass][1])
              + wt.z * bf2f(g[pass][2]) + wt.w * bf2f(g[pass][3]);
      As2[buf][cl][p] = v;
    }
  };

  int4 wcur[4], wnext[4];
  {
    const int4* wp = (const int4*)(wrow);           // slice 0
#pragma unroll
    for (int q = 0; q < 4; ++q) wcur[q] = wp[q];
  }
  ISSUE(0);
  WRITE(0, 0);
  __syncthreads();

  for (int t = 0; t < NT; ++t) {
    const int buf = t & 1;
    if (t + 1 < NT) {
      const int4* wp = (const int4*)(wrow + (t + 1) * 32);
#pragma unroll
      for (int q = 0; q < 4; ++q) wnext[q] = wp[q];
      ISSUE(t + 1);                   // global loads in flight during dot
    }
    // ---- dot: acc[p] += w[c] * As2[buf][c][p], c = 0..31
#pragma unroll
    for (int q = 0; q < 4; ++q) {
      union { int4 v; ushort u[8]; } wq; wq.v = wcur[q];
#pragma unroll
      for (int e = 0; e < 8; ++e) {
        float wv = bf2f(wq.u[e]);
        const float* ap = &As2[buf][q * 8 + e][0];
#pragma unroll
        for (int p = 0; p < 32; ++p) acc[p] = fmaf(wv, ap[p], acc[p]);
      }
    }
    if (t + 1 < NT) WRITE(t + 1, buf ^ 1);   // waitcnt lands here, post-dot
    __syncthreads();
#pragma unroll
    for (int q = 0; q < 4; ++q) wcur[q] = wnext[q];
  }

  // ---- epilogue: o = tid, 32 contiguous pixels, float4 stores
  float cbv = convb[tid];
  float* op = out + (size_t)(b * COUT + tid) * HW + h * WW + w0;
#pragma unroll
  for (int pq = 0; pq < 8; ++pq) {
    f32x4v v = { acc[pq * 4 + 0] + cbv, acc[pq * 4 + 1] + cbv,
                 acc[pq * 4 + 2] + cbv, acc[pq * 4 + 3] + cbv };
    *(f32x4v*)(op + pq * 4) = v;
  }
}

extern "C" void kernel_launch(void* const* d_in, const int* in_sizes, int n_in,
                              void* d_out, int out_size, void* d_ws, size_t ws_size,
                              hipStream_t stream) {
  const float* x     = (const float*)d_in[0];
  const float* ctr   = (const float*)d_in[1];
  const float* scale = (const float*)d_in[2];
  const float* offw  = (const float*)d_in[3];
  const float* offb  = (const float*)d_in[4];
  const float* mskw  = (const float*)d_in[5];
  const float* mskb  = (const float*)d_in[6];
  const float* cw    = (const float*)d_in[7];
  const float* cb    = (const float*)d_in[8];
  float* out = (float*)d_out;

  ushort* xT = (ushort*)d_ws;                                     // 16.78 MB
  ushort* Bm = (ushort*)((char*)d_ws + (size_t)2 * XT_PER_B * 2); // +1.18 MB

  k_transpose<<<dim3(1024), dim3(256), 0, stream>>>(x, xT);
  k_packw<<<dim3(2304), dim3(256), 0, stream>>>(cw, Bm);
  k_main2<<<dim3(1024), dim3(256), 0, stream>>>(xT, Bm, scale, ctr, offw, offb,
                                                mskw, mskb, cb, out);
}

// Round 6
// 635.541 us; speedup vs baseline: 61.9109x; 61.9109x over previous
//
#include <hip/hip_runtime.h>

// FeatureAdaptation (deformable conv): B=2, CHI=CHO=256, H=W=128, K=9.
// R6: register-blocked VALU GEMM (8 out-ch x 4 px per thread).
//  - R2-verified gather/metadata/transpose/pack, byte-identical math
//  - fixes R2's LDS-broadcast bound (1024 b32 -> 32 b128 per slice per thread)
//  - fixes R5's scratch spill (no lambdas/unions; constant-indexed arrays only)

typedef float f32x4v __attribute__((ext_vector_type(4)));

#define HH 128
#define WW 128
#define CIN 256
#define COUT 256
#define KK9 9
#define HW (HH * WW)            // 16384
#define KDIM (KK9 * CIN)        // 2304
#define NT (KDIM / 32)          // 72 slices of 32
#define BM 32
#define XT_PER_B (HW * CIN)     // 4194304 elems per batch

__device__ __forceinline__ ushort f2bf(float f) {
  union { float f; unsigned u; } v; v.f = f;
  unsigned u = v.u;
  u += 0x7FFFu + ((u >> 16) & 1u);   // RNE
  return (ushort)(u >> 16);
}
__device__ __forceinline__ float bf2f(ushort h) {
  return __uint_as_float(((unsigned)h) << 16);
}

// ---------------- x (B,C,H,W) f32  ->  xT (B,H,W,C) bf16 ----------------
__global__ __launch_bounds__(256) void k_transpose(const float* __restrict__ x,
                                                   ushort* __restrict__ xT) {
  __shared__ ushort tile[64][130];
  const int bid = blockIdx.x;       // ((b*4 + cb)*128 + y)
  const int y  = bid & 127;
  const int t  = bid >> 7;
  const int cb = t & 3;
  const int b  = t >> 2;

  const int xl = threadIdx.x & 127;
  const int ch = threadIdx.x >> 7;
  const float* src = x + (size_t)(b * CIN + cb * 64) * HW + y * WW + xl;
#pragma unroll
  for (int i = 0; i < 32; ++i) {
    int c = ch * 32 + i;
    tile[c][xl] = f2bf(src[(size_t)c * HW]);
  }
  __syncthreads();
  const int c  = threadIdx.x & 63;
  const int xh = threadIdx.x >> 6;
  ushort* dst = xT + (size_t)b * XT_PER_B + (size_t)(y * WW) * CIN + cb * 64 + c;
#pragma unroll
  for (int i = 0; i < 32; ++i) {
    int xx = xh * 32 + i;
    dst[(size_t)xx * CIN] = tile[c][xx];
  }
}

// ---------------- conv_w (O,C,3,3) f32 -> Bm[o][k*256+c] bf16 ----------------
__global__ __launch_bounds__(256) void k_packw(const float* __restrict__ cw,
                                               ushort* __restrict__ Bm) {
  int idx = blockIdx.x * 256 + threadIdx.x;   // < 589824
  int o = idx / KDIM;
  int t = idx - o * KDIM;
  int k = t >> 8;
  int c = t & 255;
  Bm[idx] = f2bf(cw[(o * CIN + c) * KK9 + k]);
}

// weight component select: e is a compile-time constant under full unroll
__device__ __forceinline__ float wsel(const int4& w, int e) {
  int comp = ((e >> 1) == 0) ? w.x : ((e >> 1) == 1) ? w.y
           : ((e >> 1) == 2) ? w.z : w.w;
  return (e & 1) ? __uint_as_float((unsigned)comp & 0xffff0000u)
                 : __uint_as_float(((unsigned)comp) << 16);
}

// ---------------- gather + register-blocked VALU GEMM ----------------
// grid 1024 = B*H*(W/32); block 256. Block tile: 32 pixels x 256 out-ch.
// Thread (og = tid>>3, pg = tid&7) owns channels og*8..+7, pixels pg*4..+3.
__global__ __launch_bounds__(256) void k_main3(
    const ushort* __restrict__ xT, const ushort* __restrict__ Bm,
    const float* __restrict__ scale, const float* __restrict__ ctr,
    const float* __restrict__ offw, const float* __restrict__ offb,
    const float* __restrict__ mskw, const float* __restrict__ mskb,
    const float* __restrict__ convb, float* __restrict__ out) {
  __shared__ __align__(16) float As2[32][36];   // rows 144B: 16B-aligned, bank-spread
  __shared__ int4   moff[BM * KK9];
  __shared__ float4 mwt[BM * KK9];

  const int tid  = threadIdx.x;
  const int lane = tid & 63;
  const int wid  = tid >> 6;
  const int og   = tid >> 3;        // 0..31: channel group (8 ch)
  const int pg   = tid & 7;         // 0..7 : pixel group (4 px)
  const int mb   = blockIdx.x;
  const int b    = mb >> 9;
  const int rem  = mb & 511;
  const int h    = rem >> 2;
  const int w0   = (rem & 3) << 5;

  // ---- prologue: per (pixel,k) bilinear metadata (R2-verified)
  for (int idx = tid; idx < BM * KK9; idx += 256) {
    int p = idx / 9;
    int k = idx - p * 9;
    int w = w0 + p;
    float sc = scale[b * HW + h * WW + w];
    float ct = ctr[b * HW + h * WW + w];
    float dy = sc * offw[2 * k]     + offb[2 * k];
    float dx = sc * offw[2 * k + 1] + offb[2 * k + 1];
    float mk = 1.0f / (1.0f + __expf(-(ct * mskw[k] + mskb[k])));
    float ys = (float)(h + (k / 3) - 1) + dy;
    float xs = (float)(w + (k % 3) - 1) + dx;
    float y0 = floorf(ys), x0 = floorf(xs);
    float wy1 = ys - y0, wx1 = xs - x0;
    float wy0 = 1.f - wy1, wx0 = 1.f - wx1;
    int offc[4]; float wtc[4];
#pragma unroll
    for (int a = 0; a < 2; ++a)
#pragma unroll
      for (int bb = 0; bb < 2; ++bb) {
        float yc = y0 + (float)a, xc = x0 + (float)bb;
        bool valid = (yc >= 0.f) && (yc <= 127.f) && (xc >= 0.f) && (xc <= 127.f);
        int yi = (int)fminf(fmaxf(yc, 0.f), 127.f);
        int xi = (int)fminf(fmaxf(xc, 0.f), 127.f);
        offc[a * 2 + bb] = (yi * WW + xi) * CIN;
        wtc[a * 2 + bb]  = (a ? wy1 : wy0) * (bb ? wx1 : wx0) * mk * (valid ? 1.f : 0.f);
      }
    moff[idx] = make_int4(offc[0], offc[1], offc[2], offc[3]);
    mwt[idx]  = make_float4(wtc[0], wtc[1], wtc[2], wtc[3]);
  }
  __syncthreads();

  const ushort* xTb = xT + (size_t)b * XT_PER_B;
  const int cl   = lane & 31;          // channel lane (coalesced gather)
  const int half = lane >> 5;

  f32x4v acc[8];
#pragma unroll
  for (int j = 0; j < 8; ++j) acc[j] = (f32x4v){0.f, 0.f, 0.f, 0.f};

  const ushort* wrow = Bm + (size_t)og * 8 * KDIM;   // 8 channel rows

  for (int t = 0; t < NT; ++t) {
    // ---- gather 32c x 32px slice into As2 (coalesced 2B x 32-lane loads)
    const int k  = t >> 3;
    const int c0 = (t & 7) << 5;
    const int c  = c0 + cl;
#pragma unroll
    for (int pass = 0; pass < 4; ++pass) {
      int p   = wid * 8 + pass * 2 + half;
      int idx = p * 9 + k;
      int4   off = moff[idx];
      float4 wt  = mwt[idx];
      As2[cl][p] = wt.x * bf2f(xTb[off.x + c]) + wt.y * bf2f(xTb[off.y + c])
                 + wt.z * bf2f(xTb[off.z + c]) + wt.w * bf2f(xTb[off.w + c]);
    }
    __syncthreads();

    // ---- dot: acc[j][*] += w[ch=og*8+j][c] * As2[c][pg*4..+3]
    const size_t so = (size_t)t * 32;
#pragma unroll
    for (int q = 0; q < 4; ++q) {
      int4 wv0 = *(const int4*)(wrow + 0 * KDIM + so + q * 8);
      int4 wv1 = *(const int4*)(wrow + 1 * KDIM + so + q * 8);
      int4 wv2 = *(const int4*)(wrow + 2 * KDIM + so + q * 8);
      int4 wv3 = *(const int4*)(wrow + 3 * KDIM + so + q * 8);
      int4 wv4 = *(const int4*)(wrow + 4 * KDIM + so + q * 8);
      int4 wv5 = *(const int4*)(wrow + 5 * KDIM + so + q * 8);
      int4 wv6 = *(const int4*)(wrow + 6 * KDIM + so + q * 8);
      int4 wv7 = *(const int4*)(wrow + 7 * KDIM + so + q * 8);
#pragma unroll
      for (int e = 0; e < 8; ++e) {
        f32x4v a = *(const f32x4v*)(&As2[q * 8 + e][pg * 4]);
        acc[0] += wsel(wv0, e) * a;
        acc[1] += wsel(wv1, e) * a;
        acc[2] += wsel(wv2, e) * a;
        acc[3] += wsel(wv3, e) * a;
        acc[4] += wsel(wv4, e) * a;
        acc[5] += wsel(wv5, e) * a;
        acc[6] += wsel(wv6, e) * a;
        acc[7] += wsel(wv7, e) * a;
      }
    }
    __syncthreads();
  }

  // ---- epilogue: 8 channels x 4 contiguous pixels, float4 stores
#pragma unroll
  for (int j = 0; j < 8; ++j) {
    int ch = og * 8 + j;
    float cbv = convb[ch];
    f32x4v v = acc[j];
    v.x += cbv; v.y += cbv; v.z += cbv; v.w += cbv;
    *(f32x4v*)(out + (size_t)(b * COUT + ch) * HW + h * WW + w0 + pg * 4) = v;
  }
}

extern "C" void kernel_launch(void* const* d_in, const int* in_sizes, int n_in,
                              void* d_out, int out_size, void* d_ws, size_t ws_size,
                              hipStream_t stream) {
  const float* x     = (const float*)d_in[0];
  const float* ctr   = (const float*)d_in[1];
  const float* scale = (const float*)d_in[2];
  const float* offw  = (const float*)d_in[3];
  const float* offb  = (const float*)d_in[4];
  const float* mskw  = (const float*)d_in[5];
  const float* mskb  = (const float*)d_in[6];
  const float* cw    = (const float*)d_in[7];
  const float* cb    = (const float*)d_in[8];
  float* out = (float*)d_out;

  ushort* xT = (ushort*)d_ws;                                     // 16.78 MB
  ushort* Bm = (ushort*)((char*)d_ws + (size_t)2 * XT_PER_B * 2); // +1.18 MB

  k_transpose<<<dim3(1024), dim3(256), 0, stream>>>(x, xT);
  k_packw<<<dim3(2304), dim3(256), 0, stream>>>(cw, Bm);
  k_main3<<<dim3(1024), dim3(256), 0, stream>>>(xT, Bm, scale, ctr, offw, offb,
                                                mskw, mskb, cb, out);
}